// Round 11
// baseline (92.061 us; speedup 1.0000x reference)
//
#include <hip/hip_runtime.h>

// GSICell. out[n] = sum_{e: dst=n} eattr[s%100, d%100] * <feat38(x_i,x_j), wc_eff> + <feat12(x[n]), wf_eff>
// wc_eff[k] = c_mask[k]*(wc2[k]-wc2[k+38]); wf_eff[k] = f_mask[k]*(wf2[k]-wf2[k+12])
//
// R10 post-mortem: 2:2 LDS/VMEM pipe balance won (90.7->89.1) but each thread owns
// exactly ONE 4-edge chunk, so divergent VMEM (x[s], eattr) sat on the critical
// path AFTER the staging barrier, un-overlapped. R11: peel the first chunk and
// hoist idx->xj->ea loads BEFORE staging, so the VMEM stream overlaps the LDS
// staging phase; post-barrier work = xs[d] read + math + ds_add (LDS only).

#define NCL 38
#define NFL 12
#define NMAX 10240
#define GRP 4          // thread-groups per reduce block (each sums B/GRP rows)

__device__ __forceinline__ float frcp(float v) { return __builtin_amdgcn_rcpf(v); }

// _safe_inv: 1.0 / (|v|<eps ? sign(v)*eps : v), eps=1e-2, sign(0)=+1
__device__ __forceinline__ float safe_inv(float v) {
    float den = (fabsf(v) < 0.01f) ? ((v >= 0.0f) ? 0.01f : -0.01f) : v;
    return frcp(den);
}

// 38-term edge library dotted with wc_eff on the fly (w = LDS pointer).
__device__ __forceinline__ float edge_msg(float xi, float xj, const float* w) {
    float d = xj - xi;
    float s = xj + xi;
    float acc;
    acc  = w[0] * xi + w[1] * xj + w[2] * d;
    acc += w[3] * (xi * xi) + w[4] * (xj * xj) + w[5] * (d * d);
    float ii = safe_inv(xi), ij = safe_inv(xj), id = safe_inv(d), is = safe_inv(s);
    acc += w[6] * ii + w[7] * ij + w[8] * id + w[9] * is;
    acc += w[10] * (ii * ii) + w[11] * (ij * ij) + w[12] * (id * id) + w[13] * (is * is);
    float sd = __sinf(d), cd = __cosf(d);
    float ss = __sinf(s), cs = __cosf(s);
    float si = __sinf(xi), ci = __cosf(xi);
    float sj = __sinf(xj), cj = __cosf(xj);
    acc += w[14] * sd + w[15] * cd + w[16] * ss + w[17] * cs;
    acc += w[18] * si + w[19] * ci + w[20] * sj + w[21] * cj;
    acc += w[22] * (xi * xj) + w[23] * (xi * sj) + w[24] * (xj * si) + w[25] * (sd * cs);
    {
        float e = __expf(xi), e2 = e * e;
        acc += w[26] * ((e2 - 1.f) * frcp(e2 + 1.f)) + w[27] * (e * frcp(e + 1.f)) + w[28] * fmaxf(xi, 0.f);
    }
    {
        float e = __expf(xj), e2 = e * e;
        acc += w[29] * ((e2 - 1.f) * frcp(e2 + 1.f)) + w[30] * (e * frcp(e + 1.f)) + w[31] * fmaxf(xj, 0.f);
    }
    {
        float e = __expf(d), e2 = e * e;
        acc += w[32] * ((e2 - 1.f) * frcp(e2 + 1.f)) + w[33] * (e * frcp(e + 1.f)) + w[34] * fmaxf(d, 0.f);
    }
    {
        float e = __expf(s), e2 = e * e;
        acc += w[35] * ((e2 - 1.f) * frcp(e2 + 1.f)) + w[36] * (e * frcp(e + 1.f)) + w[37] * fmaxf(s, 0.f);
    }
    return acc;
}

// Node library: [1, sin, cos, x*sin, x, x^2, inv, inv^2, inv^3, tanh, sigmoid, relu]
__device__ __forceinline__ float node_F(float v, const float* wf) {
    float sv = __sinf(v), cv = __cosf(v);
    float iv = safe_inv(v);
    float e  = __expf(v), e2 = e * e;
    float th = (e2 - 1.f) * frcp(e2 + 1.f);
    float sg = e * frcp(e + 1.f);
    return wf[0] + wf[1] * sv + wf[2] * cv + wf[3] * (v * sv)
         + wf[4] * v + wf[5] * (v * v)
         + wf[6] * iv + wf[7] * (iv * iv) + wf[8] * (iv * iv * iv)
         + wf[9] * th + wf[10] * sg + wf[11] * fmaxf(v, 0.f);
}

// ---------------- Kernel 1: edge accumulation, VMEM hoisted over staging ----------------

__global__ void __launch_bounds__(1024) edge_lds_kernel(
        const float* __restrict__ x,
        const int* __restrict__ ei,           // [2, E] int32
        const float* __restrict__ eattr,      // [100, 100]
        const float* __restrict__ c_mask,
        const float* __restrict__ wc2,
        float* __restrict__ scratch,          // [gridDim.x, N] partials
        int E, int N) {
    __shared__ float w[NCL];
    __shared__ float acc[NMAX];               // 40 KB accumulator (LDS pipe)
    __shared__ float xs[NMAX];                // 40 KB node states (LDS pipe)

    const int T = gridDim.x * 1024;
    const int t = blockIdx.x * 1024 + threadIdx.x;
    const int E4 = E & ~3;

    // ---- peel chunk 0: issue ALL divergent VMEM before touching LDS ----
    int e0 = 4 * t;
    int ss0[4], dd0[4];
    float xj0[4], ea0[4];
    const bool have0 = (e0 < E4);
    if (have0) {
        int4 s4 = *(const int4*)(ei + e0);        // 16B coalesced (HBM stream)
        int4 d4 = *(const int4*)(ei + E + e0);
        ss0[0] = s4.x; ss0[1] = s4.y; ss0[2] = s4.z; ss0[3] = s4.w;
        dd0[0] = d4.x; dd0[1] = d4.y; dd0[2] = d4.z; dd0[3] = d4.w;
#pragma unroll
        for (int k = 0; k < 4; ++k) {
            xj0[k] = x[ss0[k]];                                    // VMEM divergent
            ea0[k] = eattr[(ss0[k] % 100) * 100 + (dd0[k] % 100)]; // VMEM divergent
        }
    }

    // ---- staging (overlaps the in-flight VMEM above) ----
    if (threadIdx.x < NCL)
        w[threadIdx.x] = c_mask[threadIdx.x] * (wc2[threadIdx.x] - wc2[threadIdx.x + NCL]);
    {
        float4* a4 = (float4*)acc;
        for (int i = threadIdx.x; i < NMAX / 4; i += 1024) a4[i] = make_float4(0.f, 0.f, 0.f, 0.f);
        float4* x4 = (float4*)xs;
        int nx4 = N / 4;
        const float4* gx4 = (const float4*)x;
        for (int i = threadIdx.x; i < nx4; i += 1024) x4[i] = gx4[i];
        for (int i = 4 * nx4 + threadIdx.x; i < N; i += 1024) xs[i] = x[i];
    }
    __syncthreads();

    // ---- chunk 0 compute: LDS-only divergent ops ----
    if (have0) {
#pragma unroll
        for (int k = 0; k < 4; ++k) {
            int d = dd0[k];
            float m = edge_msg(xs[d], xj0[k], w);   // xs[d]: ds_read
            atomicAdd(&acc[d], ea0[k] * m);         // ds_add_f32
        }
    }

    // ---- remaining chunks (only if E > 4*T; vestigial for this problem) ----
    for (e0 += 4 * T; e0 < E4; e0 += 4 * T) {
        int4 s4 = *(const int4*)(ei + e0);
        int4 d4 = *(const int4*)(ei + E + e0);
        int ss[4] = {s4.x, s4.y, s4.z, s4.w};
        int dd[4] = {d4.x, d4.y, d4.z, d4.w};
#pragma unroll
        for (int k = 0; k < 4; ++k) {
            int s = ss[k], d = dd[k];
            float m  = edge_msg(xs[d], x[s], w);
            float ea = eattr[(s % 100) * 100 + (d % 100)];
            atomicAdd(&acc[d], ea * m);
        }
    }
    if (t == 0) {                                  // tail (E % 4), usually empty
        for (int e = E4; e < E; ++e) {
            int s = ei[e], d = ei[E + e];
            float m  = edge_msg(xs[d], x[s], w);
            float ea = eattr[(s % 100) * 100 + (d % 100)];
            atomicAdd(&acc[d], ea * m);
        }
    }
    __syncthreads();
    // coalesced float4 flush
    float4* dst4 = (float4*)(scratch + (size_t)blockIdx.x * N);
    const float4* a4 = (const float4*)acc;
    int n4 = N / 4;
    for (int i = threadIdx.x; i < n4; i += 1024) dst4[i] = a4[i];
    for (int i = 4 * n4 + threadIdx.x; i < N; i += 1024)
        scratch[(size_t)blockIdx.x * N + i] = acc[i];
}

// ---------------- Kernel 2: fused reduction + node library + out write ----------------

__global__ void __launch_bounds__(256) reduce_fused_kernel(
        const float* __restrict__ scratch,    // [B][N]
        const float* __restrict__ x,
        const float* __restrict__ f_mask,
        const float* __restrict__ wf2,
        float* __restrict__ out, int N, int B) {
    __shared__ float wf[NFL];
    __shared__ float part[GRP][64];
    if (threadIdx.x < NFL)
        wf[threadIdx.x] = f_mask[threadIdx.x] * (wf2[threadIdx.x] - wf2[threadIdx.x + NFL]);

    const int lane = threadIdx.x & 63;        // node column within block
    const int g    = threadIdx.x >> 6;        // row group
    const int n    = blockIdx.x * 64 + lane;
    const int per  = B / GRP;

    float sum = 0.f;
    if (n < N) {
        const float* p = scratch + (size_t)(g * per) * N + n;
#pragma unroll 8
        for (int b = 0; b < per; ++b) sum += p[(size_t)b * N];   // coalesced per iter
    }
    part[g][lane] = sum;
    __syncthreads();
    if (g == 0 && n < N) {
        float tot = node_F(x[n], wf);
#pragma unroll
        for (int gg = 0; gg < GRP; ++gg) tot += part[gg][lane];
        out[n] = tot;
    }
}

// ---------------- Fallback path (R3, proven): global hw atomics ----------------

__global__ void __launch_bounds__(256) node_kernel(
        const float* __restrict__ x,
        const float* __restrict__ f_mask,
        const float* __restrict__ wf2,
        float* __restrict__ out, int n) {
    __shared__ float wf[NFL];
    if (threadIdx.x < NFL)
        wf[threadIdx.x] = f_mask[threadIdx.x] * (wf2[threadIdx.x] - wf2[threadIdx.x + NFL]);
    __syncthreads();
    int i = blockIdx.x * blockDim.x + threadIdx.x;
    if (i >= n) return;
    out[i] = node_F(x[i], wf);
}

__global__ void __launch_bounds__(256) edge_atomic_kernel(
        const float* __restrict__ x,
        const int* __restrict__ ei,
        const float* __restrict__ eattr,
        const float* __restrict__ c_mask,
        const float* __restrict__ wc2,
        float* __restrict__ out,
        int E) {
    __shared__ float w[NCL];
    if (threadIdx.x < NCL)
        w[threadIdx.x] = c_mask[threadIdx.x] * (wc2[threadIdx.x] - wc2[threadIdx.x + NCL]);
    __syncthreads();
    int t  = blockIdx.x * blockDim.x + threadIdx.x;
    int e0 = 4 * t;
    if (e0 + 3 < E) {
        int4 s4 = *(const int4*)(ei + e0);
        int4 d4 = *(const int4*)(ei + E + e0);
        int ss[4] = {s4.x, s4.y, s4.z, s4.w};
        int dd[4] = {d4.x, d4.y, d4.z, d4.w};
#pragma unroll
        for (int k = 0; k < 4; ++k) {
            int s = ss[k], d = dd[k];
            float m  = edge_msg(x[d], x[s], w);
            float ea = eattr[(s % 100) * 100 + (d % 100)];
            unsafeAtomicAdd(out + d, ea * m);
        }
    } else {
        for (int e = e0; e < E; ++e) {
            int s = ei[e], d = ei[E + e];
            float m  = edge_msg(x[d], x[s], w);
            float ea = eattr[(s % 100) * 100 + (d % 100)];
            unsafeAtomicAdd(out + d, ea * m);
        }
    }
}

extern "C" void kernel_launch(void* const* d_in, const int* in_sizes, int n_in,
                              void* d_out, int out_size, void* d_ws, size_t ws_size,
                              hipStream_t stream) {
    // inputs: 0=t, 1=x[N], 2=edge_index[2*E] int32, 3=c_mask[38], 4=f_mask[12],
    //         5=wc_2[76], 6=wf_2[24], 7=edge_attr_all[100*100]
    const float* x      = (const float*)d_in[1];
    const int*   ei     = (const int*)d_in[2];
    const float* c_mask = (const float*)d_in[3];
    const float* f_mask = (const float*)d_in[4];
    const float* wc2    = (const float*)d_in[5];
    const float* wf2    = (const float*)d_in[6];
    const float* eattr  = (const float*)d_in[7];
    float* out = (float*)d_out;

    int N = in_sizes[1];
    int E = in_sizes[2] / 2;

    // pick partial-count B by available scratch: B * N * 4 bytes (B % GRP == 0)
    int B = 0;
    if (N <= NMAX) {
        const int tiers[3] = {256, 128, 64};   // B=256 proven best (R8 vs R9)
        for (int i = 0; i < 3; ++i) {
            size_t need = (size_t)tiers[i] * (size_t)N * 4;
            if (ws_size >= need) { B = tiers[i]; break; }
        }
    }

    if (B) {
        float* scratch = (float*)d_ws;                 // [B][N]
        edge_lds_kernel<<<B, 1024, 0, stream>>>(x, ei, eattr, c_mask, wc2, scratch, E, N);
        reduce_fused_kernel<<<(N + 63) / 64, 256, 0, stream>>>(scratch, x, f_mask, wf2, out, N, B);
    } else {
        node_kernel<<<(N + 255) / 256, 256, 0, stream>>>(x, f_mask, wf2, out, N);
        int threads = (E + 3) / 4;
        edge_atomic_kernel<<<(threads + 255) / 256, 256, 0, stream>>>(x, ei, eattr, c_mask, wc2, out, E);
    }
}

// Round 12
// 89.626 us; speedup vs baseline: 1.0272x; 1.0272x over previous
//
#include <hip/hip_runtime.h>

// GSICell. out[n] = sum_{e: dst=n} eattr[s%100, d%100] * <feat38(x_i,x_j), wc_eff> + <feat12(x[n]), wf_eff>
// wc_eff[k] = c_mask[k]*(wc2[k]-wc2[k+38]); wf_eff[k] = f_mask[k]*(wf2[k]-wf2[k+12])
//
// FINAL (R12) = exact revert to R10, the measured best (89.1us).
// Converged model: edge kernel bound by divergent-address processing
// (~1 cyc/lane-addr/pipe; verified by R8->R10 delta = 1.6us for 1M lane-addrs),
// 4 divergent ops/edge irreducible, balanced 2:2 LDS:VMEM. Harness-fixed cost
// ~69us (41us d_ws 256MiB re-poison + restores/replay). R9 (occupancy) and
// R11 (vmem hoist; vmcnt is issue-ordered so overlap is serialized) both regressed.

#define NCL 38
#define NFL 12
#define NMAX 10240
#define GRP 4          // thread-groups per reduce block (each sums B/GRP rows)

__device__ __forceinline__ float frcp(float v) { return __builtin_amdgcn_rcpf(v); }

// _safe_inv: 1.0 / (|v|<eps ? sign(v)*eps : v), eps=1e-2, sign(0)=+1
__device__ __forceinline__ float safe_inv(float v) {
    float den = (fabsf(v) < 0.01f) ? ((v >= 0.0f) ? 0.01f : -0.01f) : v;
    return frcp(den);
}

// 38-term edge library dotted with wc_eff on the fly (w = LDS pointer).
__device__ __forceinline__ float edge_msg(float xi, float xj, const float* w) {
    float d = xj - xi;
    float s = xj + xi;
    float acc;
    acc  = w[0] * xi + w[1] * xj + w[2] * d;
    acc += w[3] * (xi * xi) + w[4] * (xj * xj) + w[5] * (d * d);
    float ii = safe_inv(xi), ij = safe_inv(xj), id = safe_inv(d), is = safe_inv(s);
    acc += w[6] * ii + w[7] * ij + w[8] * id + w[9] * is;
    acc += w[10] * (ii * ii) + w[11] * (ij * ij) + w[12] * (id * id) + w[13] * (is * is);
    float sd = __sinf(d), cd = __cosf(d);
    float ss = __sinf(s), cs = __cosf(s);
    float si = __sinf(xi), ci = __cosf(xi);
    float sj = __sinf(xj), cj = __cosf(xj);
    acc += w[14] * sd + w[15] * cd + w[16] * ss + w[17] * cs;
    acc += w[18] * si + w[19] * ci + w[20] * sj + w[21] * cj;
    acc += w[22] * (xi * xj) + w[23] * (xi * sj) + w[24] * (xj * si) + w[25] * (sd * cs);
    {
        float e = __expf(xi), e2 = e * e;
        acc += w[26] * ((e2 - 1.f) * frcp(e2 + 1.f)) + w[27] * (e * frcp(e + 1.f)) + w[28] * fmaxf(xi, 0.f);
    }
    {
        float e = __expf(xj), e2 = e * e;
        acc += w[29] * ((e2 - 1.f) * frcp(e2 + 1.f)) + w[30] * (e * frcp(e + 1.f)) + w[31] * fmaxf(xj, 0.f);
    }
    {
        float e = __expf(d), e2 = e * e;
        acc += w[32] * ((e2 - 1.f) * frcp(e2 + 1.f)) + w[33] * (e * frcp(e + 1.f)) + w[34] * fmaxf(d, 0.f);
    }
    {
        float e = __expf(s), e2 = e * e;
        acc += w[35] * ((e2 - 1.f) * frcp(e2 + 1.f)) + w[36] * (e * frcp(e + 1.f)) + w[37] * fmaxf(s, 0.f);
    }
    return acc;
}

// Node library: [1, sin, cos, x*sin, x, x^2, inv, inv^2, inv^3, tanh, sigmoid, relu]
__device__ __forceinline__ float node_F(float v, const float* wf) {
    float sv = __sinf(v), cv = __cosf(v);
    float iv = safe_inv(v);
    float e  = __expf(v), e2 = e * e;
    float th = (e2 - 1.f) * frcp(e2 + 1.f);
    float sg = e * frcp(e + 1.f);
    return wf[0] + wf[1] * sv + wf[2] * cv + wf[3] * (v * sv)
         + wf[4] * v + wf[5] * (v * v)
         + wf[6] * iv + wf[7] * (iv * iv) + wf[8] * (iv * iv * iv)
         + wf[9] * th + wf[10] * sg + wf[11] * fmaxf(v, 0.f);
}

// ---------------- Kernel 1: edge accumulation, pipe-balanced 2:2 ----------------

__global__ void __launch_bounds__(1024) edge_lds_kernel(
        const float* __restrict__ x,
        const int* __restrict__ ei,           // [2, E] int32
        const float* __restrict__ eattr,      // [100, 100]
        const float* __restrict__ c_mask,
        const float* __restrict__ wc2,
        float* __restrict__ scratch,          // [gridDim.x, N] partials
        int E, int N) {
    __shared__ float w[NCL];
    __shared__ float acc[NMAX];               // 40 KB accumulator (LDS pipe: ds_add)
    __shared__ float xs[NMAX];                // 40 KB node states (LDS pipe: x[dst])
    if (threadIdx.x < NCL)
        w[threadIdx.x] = c_mask[threadIdx.x] * (wc2[threadIdx.x] - wc2[threadIdx.x + NCL]);
    {   // zero acc + stage x (coalesced float4)
        float4* a4 = (float4*)acc;
        for (int i = threadIdx.x; i < NMAX / 4; i += 1024) a4[i] = make_float4(0.f, 0.f, 0.f, 0.f);
        float4* x4 = (float4*)xs;
        int nx4 = N / 4;
        const float4* gx4 = (const float4*)x;
        for (int i = threadIdx.x; i < nx4; i += 1024) x4[i] = gx4[i];
        for (int i = 4 * nx4 + threadIdx.x; i < N; i += 1024) xs[i] = x[i];
    }
    __syncthreads();

    const int T = gridDim.x * 1024;
    const int t = blockIdx.x * 1024 + threadIdx.x;
    const int E4 = E & ~3;
    for (int e0 = 4 * t; e0 < E4; e0 += 4 * T) {
        int4 s4 = *(const int4*)(ei + e0);        // 16B coalesced
        int4 d4 = *(const int4*)(ei + E + e0);    // E % 4 == 0 -> aligned
        int ss[4] = {s4.x, s4.y, s4.z, s4.w};
        int dd[4] = {d4.x, d4.y, d4.z, d4.w};
#pragma unroll
        for (int k = 0; k < 4; ++k) {
            int s = ss[k], d = dd[k];
            float xi = xs[d];                               // LDS pipe
            float xj = x[s];                                // VMEM pipe
            float ea = eattr[(s % 100) * 100 + (d % 100)];  // VMEM pipe
            float m  = edge_msg(xi, xj, w);
            atomicAdd(&acc[d], ea * m);                     // LDS pipe (ds_add_f32)
        }
    }
    if (t == 0) {                                  // tail (E % 4), usually empty
        for (int e = E4; e < E; ++e) {
            int s = ei[e], d = ei[E + e];
            float m  = edge_msg(xs[d], x[s], w);
            float ea = eattr[(s % 100) * 100 + (d % 100)];
            atomicAdd(&acc[d], ea * m);
        }
    }
    __syncthreads();
    // coalesced float4 flush
    float4* dst4 = (float4*)(scratch + (size_t)blockIdx.x * N);
    const float4* a4 = (const float4*)acc;
    int n4 = N / 4;
    for (int i = threadIdx.x; i < n4; i += 1024) dst4[i] = a4[i];
    for (int i = 4 * n4 + threadIdx.x; i < N; i += 1024)
        scratch[(size_t)blockIdx.x * N + i] = acc[i];
}

// ---------------- Kernel 2: fused reduction + node library + out write ----------------

__global__ void __launch_bounds__(256) reduce_fused_kernel(
        const float* __restrict__ scratch,    // [B][N]
        const float* __restrict__ x,
        const float* __restrict__ f_mask,
        const float* __restrict__ wf2,
        float* __restrict__ out, int N, int B) {
    __shared__ float wf[NFL];
    __shared__ float part[GRP][64];
    if (threadIdx.x < NFL)
        wf[threadIdx.x] = f_mask[threadIdx.x] * (wf2[threadIdx.x] - wf2[threadIdx.x + NFL]);

    const int lane = threadIdx.x & 63;        // node column within block
    const int g    = threadIdx.x >> 6;        // row group
    const int n    = blockIdx.x * 64 + lane;
    const int per  = B / GRP;

    float sum = 0.f;
    if (n < N) {
        const float* p = scratch + (size_t)(g * per) * N + n;
#pragma unroll 8
        for (int b = 0; b < per; ++b) sum += p[(size_t)b * N];   // coalesced per iter
    }
    part[g][lane] = sum;
    __syncthreads();
    if (g == 0 && n < N) {
        float tot = node_F(x[n], wf);
#pragma unroll
        for (int gg = 0; gg < GRP; ++gg) tot += part[gg][lane];
        out[n] = tot;
    }
}

// ---------------- Fallback path (R3, proven): global hw atomics ----------------

__global__ void __launch_bounds__(256) node_kernel(
        const float* __restrict__ x,
        const float* __restrict__ f_mask,
        const float* __restrict__ wf2,
        float* __restrict__ out, int n) {
    __shared__ float wf[NFL];
    if (threadIdx.x < NFL)
        wf[threadIdx.x] = f_mask[threadIdx.x] * (wf2[threadIdx.x] - wf2[threadIdx.x + NFL]);
    __syncthreads();
    int i = blockIdx.x * blockDim.x + threadIdx.x;
    if (i >= n) return;
    out[i] = node_F(x[i], wf);
}

__global__ void __launch_bounds__(256) edge_atomic_kernel(
        const float* __restrict__ x,
        const int* __restrict__ ei,
        const float* __restrict__ eattr,
        const float* __restrict__ c_mask,
        const float* __restrict__ wc2,
        float* __restrict__ out,
        int E) {
    __shared__ float w[NCL];
    if (threadIdx.x < NCL)
        w[threadIdx.x] = c_mask[threadIdx.x] * (wc2[threadIdx.x] - wc2[threadIdx.x + NCL]);
    __syncthreads();
    int t  = blockIdx.x * blockDim.x + threadIdx.x;
    int e0 = 4 * t;
    if (e0 + 3 < E) {
        int4 s4 = *(const int4*)(ei + e0);
        int4 d4 = *(const int4*)(ei + E + e0);
        int ss[4] = {s4.x, s4.y, s4.z, s4.w};
        int dd[4] = {d4.x, d4.y, d4.z, d4.w};
#pragma unroll
        for (int k = 0; k < 4; ++k) {
            int s = ss[k], d = dd[k];
            float m  = edge_msg(x[d], x[s], w);
            float ea = eattr[(s % 100) * 100 + (d % 100)];
            unsafeAtomicAdd(out + d, ea * m);
        }
    } else {
        for (int e = e0; e < E; ++e) {
            int s = ei[e], d = ei[E + e];
            float m  = edge_msg(x[d], x[s], w);
            float ea = eattr[(s % 100) * 100 + (d % 100)];
            unsafeAtomicAdd(out + d, ea * m);
        }
    }
}

extern "C" void kernel_launch(void* const* d_in, const int* in_sizes, int n_in,
                              void* d_out, int out_size, void* d_ws, size_t ws_size,
                              hipStream_t stream) {
    // inputs: 0=t, 1=x[N], 2=edge_index[2*E] int32, 3=c_mask[38], 4=f_mask[12],
    //         5=wc_2[76], 6=wf_2[24], 7=edge_attr_all[100*100]
    const float* x      = (const float*)d_in[1];
    const int*   ei     = (const int*)d_in[2];
    const float* c_mask = (const float*)d_in[3];
    const float* f_mask = (const float*)d_in[4];
    const float* wc2    = (const float*)d_in[5];
    const float* wf2    = (const float*)d_in[6];
    const float* eattr  = (const float*)d_in[7];
    float* out = (float*)d_out;

    int N = in_sizes[1];
    int E = in_sizes[2] / 2;

    // pick partial-count B by available scratch: B * N * 4 bytes (B % GRP == 0)
    int B = 0;
    if (N <= NMAX) {
        const int tiers[3] = {256, 128, 64};   // B=256 proven best (R8 vs R9)
        for (int i = 0; i < 3; ++i) {
            size_t need = (size_t)tiers[i] * (size_t)N * 4;
            if (ws_size >= need) { B = tiers[i]; break; }
        }
    }

    if (B) {
        float* scratch = (float*)d_ws;                 // [B][N]
        edge_lds_kernel<<<B, 1024, 0, stream>>>(x, ei, eattr, c_mask, wc2, scratch, E, N);
        reduce_fused_kernel<<<(N + 63) / 64, 256, 0, stream>>>(scratch, x, f_mask, wf2, out, N, B);
    } else {
        node_kernel<<<(N + 255) / 256, 256, 0, stream>>>(x, f_mask, wf2, out, N);
        int threads = (E + 3) / 4;
        edge_atomic_kernel<<<(threads + 255) / 256, 256, 0, stream>>>(x, ei, eattr, c_mask, wc2, out, E);
    }
}